// Round 1
// baseline (468.794 us; speedup 1.0000x reference)
//
#include <hip/hip_runtime.h>
#include <hip/hip_bf16.h>
#include <stdint.h>

// Problem constants (B=2, S=2048, D=1024, H=16, hd=64)
#define DIMD 1024
#define SEQ  2048
#define NH   16
#define MROWS 4096   // B*S

typedef __bf16 bf16_t;
typedef bf16_t bf16x8 __attribute__((ext_vector_type(8)));
typedef float  f32x4  __attribute__((ext_vector_type(4)));
typedef unsigned short u16x4 __attribute__((ext_vector_type(4)));
typedef unsigned short u16x8 __attribute__((ext_vector_type(8)));

static __device__ __forceinline__ f32x4 mfma16(bf16x8 a, bf16x8 b, f32x4 c) {
    return __builtin_amdgcn_mfma_f32_16x16x32_bf16(a, b, c, 0, 0, 0);
}

// Split fp32 into hi/lo bf16 by truncation: x ~= hi + lo with rel err <= 2^-16
static __device__ __forceinline__ void split_bf16(float x, unsigned short& h, unsigned short& l) {
    unsigned u  = __float_as_uint(x);
    unsigned short hu = (unsigned short)(u >> 16);
    float xh = __uint_as_float((unsigned)hu << 16);
    float lo = x - xh;
    h = hu;
    l = (unsigned short)(__float_as_uint(lo) >> 16);
}

// ---------------------------------------------------------------------------
// Kernel 1: 1024x1024 fp32 transpose (W -> W^T) so GEMM reads K-contiguous B
// ---------------------------------------------------------------------------
__global__ __launch_bounds__(256) void transpose1024(const float* __restrict__ W,
                                                     float* __restrict__ WT) {
    __shared__ float tile[32][33];
    int tx = threadIdx.x & 31, ty = threadIdx.x >> 5;   // 32 x 8
    int x0 = blockIdx.x * 32, y0 = blockIdx.y * 32;
    #pragma unroll
    for (int i = 0; i < 32; i += 8)
        tile[ty + i][tx] = W[(size_t)(y0 + ty + i) * DIMD + x0 + tx];
    __syncthreads();
    #pragma unroll
    for (int i = 0; i < 32; i += 8)
        WT[(size_t)(x0 + ty + i) * DIMD + y0 + tx] = tile[tx][ty + i];
}

// ---------------------------------------------------------------------------
// Kernel 2: projection GEMM  P = X @ W  via split-bf16 (3 MFMA per tile pair)
//   X: [4096,1024] fp32 row-major, WT: [1024,1024] fp32 (WT[n][k] = W[k][n])
//   outputs: hi/lo bf16 [4096,1024]
// Block 256 thr (4 waves, 2x2), tile 128x128, BK=32.
// ---------------------------------------------------------------------------
__global__ __launch_bounds__(256, 1) void proj_split_gemm(
    const float* __restrict__ X, const float* __restrict__ WT,
    unsigned short* __restrict__ outH, unsigned short* __restrict__ outL) {

    // padded to 40 u16 (80B stride): 16B-aligned rows, 2-way bank alias (free)
    __shared__ unsigned short AsH[128][40], AsL[128][40], BsH[128][40], BsL[128][40];

    const int tid  = threadIdx.x;
    const int lane = tid & 63, wave = tid >> 6;
    const int quad = lane >> 4, l16 = lane & 15;
    const int wy = wave >> 1, wx = wave & 1;          // wave 64x64 subtile
    const int m0 = blockIdx.y * 128, n0 = blockIdx.x * 128;

    f32x4 acc[4][4];
    #pragma unroll
    for (int mt = 0; mt < 4; mt++)
        #pragma unroll
        for (int nt = 0; nt < 4; nt++) acc[mt][nt] = (f32x4)0.0f;

    for (int k0 = 0; k0 < DIMD; k0 += 32) {
        // stage A[128][32] and B[128][32] fp32 -> split hi/lo bf16 in LDS
        #pragma unroll
        for (int i = 0; i < 4; i++) {
            int f = i * 256 + tid;           // 1024 float4 chunks
            int r = f >> 3, c = (f & 7) * 4;
            f32x4 a = *(const f32x4*)&X [(size_t)(m0 + r) * DIMD + k0 + c];
            f32x4 bb = *(const f32x4*)&WT[(size_t)(n0 + r) * DIMD + k0 + c];
            u16x4 ah, al, bh, bl;
            #pragma unroll
            for (int j = 0; j < 4; j++) {
                unsigned short h, l;
                split_bf16(a[j], h, l);  ah[j] = h; al[j] = l;
                split_bf16(bb[j], h, l); bh[j] = h; bl[j] = l;
            }
            *(u16x4*)&AsH[r][c] = ah;  *(u16x4*)&AsL[r][c] = al;
            *(u16x4*)&BsH[r][c] = bh;  *(u16x4*)&BsL[r][c] = bl;
        }
        __syncthreads();

        bf16x8 aH[4], aL[4], bH[4], bL[4];
        #pragma unroll
        for (int mt = 0; mt < 4; mt++) {
            int r = wy * 64 + mt * 16 + l16;
            aH[mt] = *(const bf16x8*)&AsH[r][quad * 8];
            aL[mt] = *(const bf16x8*)&AsL[r][quad * 8];
        }
        #pragma unroll
        for (int nt = 0; nt < 4; nt++) {
            int r = wx * 64 + nt * 16 + l16;
            bH[nt] = *(const bf16x8*)&BsH[r][quad * 8];
            bL[nt] = *(const bf16x8*)&BsL[r][quad * 8];
        }
        #pragma unroll
        for (int mt = 0; mt < 4; mt++)
            #pragma unroll
            for (int nt = 0; nt < 4; nt++) {
                acc[mt][nt] = mfma16(aH[mt], bH[nt], acc[mt][nt]);
                acc[mt][nt] = mfma16(aH[mt], bL[nt], acc[mt][nt]);
                acc[mt][nt] = mfma16(aL[mt], bH[nt], acc[mt][nt]);
            }
        __syncthreads();
    }

    // epilogue: split fp32 acc into hi/lo bf16 outputs
    #pragma unroll
    for (int mt = 0; mt < 4; mt++)
        #pragma unroll
        for (int nt = 0; nt < 4; nt++)
            #pragma unroll
            for (int r = 0; r < 4; r++) {
                int row = m0 + wy * 64 + mt * 16 + quad * 4 + r;
                int col = n0 + wx * 64 + nt * 16 + l16;
                unsigned short h, l;
                split_bf16(acc[mt][nt][r], h, l);
                outH[(size_t)row * DIMD + col] = h;
                outL[(size_t)row * DIMD + col] = l;
            }
}

// ---------------------------------------------------------------------------
// Kernel 3: flash attention per (b,h): S=2048, hd=64, scale = 1/32
//   QK^T via split-bf16 (3 MFMA), PV via bf16. Q-tile 128 rows per block,
//   K/V-tile 64 rows per iteration. Block 256 thr; each wave owns 32 Q rows.
// ---------------------------------------------------------------------------
__global__ __launch_bounds__(256, 1) void flash_attn(
    const unsigned short* __restrict__ qh, const unsigned short* __restrict__ ql,
    const unsigned short* __restrict__ kh, const unsigned short* __restrict__ kl,
    const unsigned short* __restrict__ vh,
    float* __restrict__ out) {

    // all strides 72 u16 = 144B: 16B-aligned, 2-way bank alias (free)
    __shared__ unsigned short KsH[64][72], KsL[64][72], VT[64][72];
    __shared__ unsigned short Ps[4][32][72];

    const int tid  = threadIdx.x;
    const int lane = tid & 63, wave = tid >> 6;
    const int quad = lane >> 4, l16 = lane & 15;
    const int bh = blockIdx.y, b = bh >> 4, h = bh & 15;
    const size_t slab = ((size_t)(b * SEQ + h * 128)) * DIMD;  // elem offset of head slab
    const int q0 = blockIdx.x * 128;
    const float cscale = 0.03125f * 1.44269504089f;            // scale * log2(e)

    // Q fragments in registers (hi/lo), rows wave*32 + mt*16 + l16
    bf16x8 qfH[2][2], qfL[2][2];
    #pragma unroll
    for (int mt = 0; mt < 2; mt++) {
        int r2 = q0 + wave * 32 + mt * 16 + l16;
        #pragma unroll
        for (int kk = 0; kk < 2; kk++) {
            int c = kk * 32 + quad * 8;
            qfH[mt][kk] = *(const bf16x8*)(qh + slab + (size_t)r2 * 64 + c);
            qfL[mt][kk] = *(const bf16x8*)(ql + slab + (size_t)r2 * 64 + c);
        }
    }

    f32x4 O[2][4];
    float M[2][4], L[2][4];
    #pragma unroll
    for (int mt = 0; mt < 2; mt++)
        #pragma unroll
        for (int r = 0; r < 4; r++) {
            M[mt][r] = -3.0e38f; L[mt][r] = 0.0f;
            if (r < 4) {}
        }
    #pragma unroll
    for (int mt = 0; mt < 2; mt++)
        #pragma unroll
        for (int nv = 0; nv < 4; nv++) O[mt][nv] = (f32x4)0.0f;

    for (int j0 = 0; j0 < SEQ; j0 += 64) {
        // stage K hi/lo [64][64] and V^T [64][64]
        #pragma unroll
        for (int i = 0; i < 2; i++) {
            int f = i * 256 + tid;           // 512 chunks of 8 u16
            int r = f >> 3, c = (f & 7) * 8;
            const size_t g = slab + (size_t)(j0 + r) * 64 + c;
            *(u16x8*)&KsH[r][c] = *(const u16x8*)(kh + g);
            *(u16x8*)&KsL[r][c] = *(const u16x8*)(kl + g);
            u16x8 vv = *(const u16x8*)(vh + g);
            #pragma unroll
            for (int j = 0; j < 8; j++) VT[c + j][r] = vv[j];
        }
        __syncthreads();

        // S = Q K^T (split: Ah*Bh + Ah*Bl + Al*Bh)
        f32x4 S[2][4];
        #pragma unroll
        for (int mt = 0; mt < 2; mt++)
            #pragma unroll
            for (int nt = 0; nt < 4; nt++) S[mt][nt] = (f32x4)0.0f;
        #pragma unroll
        for (int nt = 0; nt < 4; nt++)
            #pragma unroll
            for (int kk = 0; kk < 2; kk++) {
                int rB = nt * 16 + l16, cB = kk * 32 + quad * 8;
                bf16x8 bH = *(const bf16x8*)&KsH[rB][cB];
                bf16x8 bL = *(const bf16x8*)&KsL[rB][cB];
                #pragma unroll
                for (int mt = 0; mt < 2; mt++) {
                    S[mt][nt] = mfma16(qfH[mt][kk], bH, S[mt][nt]);
                    S[mt][nt] = mfma16(qfH[mt][kk], bL, S[mt][nt]);
                    S[mt][nt] = mfma16(qfL[mt][kk], bH, S[mt][nt]);
                }
            }

        // online softmax: row (mt, quad*4+r) stats are register-local per lane
        #pragma unroll
        for (int mt = 0; mt < 2; mt++)
            #pragma unroll
            for (int r = 0; r < 4; r++) {
                float mx = -3.0e38f;
                #pragma unroll
                for (int nt = 0; nt < 4; nt++) mx = fmaxf(mx, S[mt][nt][r]);
                #pragma unroll
                for (int d = 1; d < 16; d <<= 1) mx = fmaxf(mx, __shfl_xor(mx, d));
                float Mn = fmaxf(M[mt][r], mx);
                float al = exp2f((M[mt][r] - Mn) * cscale);
                M[mt][r] = Mn;
                float rs = 0.0f;
                #pragma unroll
                for (int nt = 0; nt < 4; nt++) {
                    float p = exp2f((S[mt][nt][r] - Mn) * cscale);
                    S[mt][nt][r] = p;
                    rs += p;
                }
                #pragma unroll
                for (int d = 1; d < 16; d <<= 1) rs += __shfl_xor(rs, d);
                L[mt][r] = L[mt][r] * al + rs;
                #pragma unroll
                for (int nv = 0; nv < 4; nv++) O[mt][nv][r] *= al;
                // write P row (bf16 trunc) to per-wave LDS for A-layout reload
                int prow = mt * 16 + quad * 4 + r;
                #pragma unroll
                for (int nt = 0; nt < 4; nt++)
                    Ps[wave][prow][nt * 16 + l16] =
                        (unsigned short)(__float_as_uint(S[mt][nt][r]) >> 16);
            }

        // O += P @ V  (bf16)
        #pragma unroll
        for (int kk = 0; kk < 2; kk++) {
            bf16x8 aP[2];
            #pragma unroll
            for (int mt = 0; mt < 2; mt++)
                aP[mt] = *(const bf16x8*)&Ps[wave][mt * 16 + l16][kk * 32 + quad * 8];
            #pragma unroll
            for (int nv = 0; nv < 4; nv++) {
                bf16x8 bV = *(const bf16x8*)&VT[nv * 16 + l16][kk * 32 + quad * 8];
                #pragma unroll
                for (int mt = 0; mt < 2; mt++)
                    O[mt][nv] = mfma16(aP[mt], bV, O[mt][nv]);
            }
        }
        __syncthreads();
    }

    // epilogue: out[b, r2, h*64 + d] = O / L
    #pragma unroll
    for (int mt = 0; mt < 2; mt++)
        #pragma unroll
        for (int r = 0; r < 4; r++) {
            float inv = 1.0f / L[mt][r];
            int r2 = q0 + wave * 32 + mt * 16 + quad * 4 + r;
            size_t obase = ((size_t)(b * SEQ + r2)) * DIMD + h * 64;
            #pragma unroll
            for (int nv = 0; nv < 4; nv++)
                out[obase + nv * 16 + l16] = O[mt][nv][r] * inv;
        }
}

// ---------------------------------------------------------------------------
extern "C" void kernel_launch(void* const* d_in, const int* in_sizes, int n_in,
                              void* d_out, int out_size, void* d_ws, size_t ws_size,
                              hipStream_t stream) {
    const float* q  = (const float*)d_in[0];
    const float* k  = (const float*)d_in[1];
    const float* v  = (const float*)d_in[2];
    const float* wq = (const float*)d_in[3];
    const float* wk = (const float*)d_in[4];
    const float* wv = (const float*)d_in[5];
    float* out = (float*)d_out;

    char* ws = (char*)d_ws;
    const size_t WT_BYTES = (size_t)DIMD * DIMD * 4;       // 4 MB
    const size_t BF_BYTES = (size_t)MROWS * DIMD * 2;      // 8 MB
    float* WTq = (float*)(ws + 0 * WT_BYTES);
    float* WTk = (float*)(ws + 1 * WT_BYTES);
    float* WTv = (float*)(ws + 2 * WT_BYTES);
    unsigned short* qh = (unsigned short*)(ws + 3 * WT_BYTES + 0 * BF_BYTES);
    unsigned short* ql = (unsigned short*)(ws + 3 * WT_BYTES + 1 * BF_BYTES);
    unsigned short* kh = (unsigned short*)(ws + 3 * WT_BYTES + 2 * BF_BYTES);
    unsigned short* kl = (unsigned short*)(ws + 3 * WT_BYTES + 3 * BF_BYTES);
    unsigned short* vh = (unsigned short*)(ws + 3 * WT_BYTES + 4 * BF_BYTES);
    unsigned short* vl = (unsigned short*)(ws + 3 * WT_BYTES + 5 * BF_BYTES);

    dim3 tg(32, 32);
    transpose1024<<<tg, 256, 0, stream>>>(wq, WTq);
    transpose1024<<<tg, 256, 0, stream>>>(wk, WTk);
    transpose1024<<<tg, 256, 0, stream>>>(wv, WTv);

    dim3 pg(DIMD / 128, MROWS / 128);  // (8, 32)
    proj_split_gemm<<<pg, 256, 0, stream>>>(q, WTq, qh, ql);
    proj_split_gemm<<<pg, 256, 0, stream>>>(k, WTk, kh, kl);
    proj_split_gemm<<<pg, 256, 0, stream>>>(v, WTv, vh, vl);

    dim3 fg(SEQ / 128, 2 * NH);        // (16, 32)
    flash_attn<<<fg, 256, 0, stream>>>(qh, ql, kh, kl, vh, out);
}

// Round 2
// 378.146 us; speedup vs baseline: 1.2397x; 1.2397x over previous
//
#include <hip/hip_runtime.h>
#include <hip/hip_bf16.h>
#include <stdint.h>

// Problem constants (B=2, S=2048, D=1024, H=16, hd=64)
#define DIMD 1024
#define SEQ  2048
#define NH   16
#define MROWS 4096   // B*S

typedef __bf16 bf16_t;
typedef bf16_t bf16x8 __attribute__((ext_vector_type(8)));
typedef float  f32x4  __attribute__((ext_vector_type(4)));
typedef unsigned short u16x4 __attribute__((ext_vector_type(4)));
typedef unsigned short u16x8 __attribute__((ext_vector_type(8)));

static __device__ __forceinline__ f32x4 mfma16(bf16x8 a, bf16x8 b, f32x4 c) {
    return __builtin_amdgcn_mfma_f32_16x16x32_bf16(a, b, c, 0, 0, 0);
}

static __device__ __forceinline__ float fast_exp2(float x) {
#if __has_builtin(__builtin_amdgcn_exp2f)
    return __builtin_amdgcn_exp2f(x);
#else
    return exp2f(x);
#endif
}

// Split fp32 into hi/lo bf16 by truncation: x ~= hi + lo with rel err <= 2^-16
static __device__ __forceinline__ void split_bf16(float x, unsigned short& h, unsigned short& l) {
    unsigned u  = __float_as_uint(x);
    unsigned short hu = (unsigned short)(u >> 16);
    float xh = __uint_as_float((unsigned)hu << 16);
    float lo = x - xh;
    h = hu;
    l = (unsigned short)(__float_as_uint(lo) >> 16);
}

// ---------------------------------------------------------------------------
// Kernel 1: 1024x1024 fp32 transpose (W -> W^T), all 3 weights in one launch
// ---------------------------------------------------------------------------
__global__ __launch_bounds__(256) void transposeW3(
    const float* __restrict__ w0, const float* __restrict__ w1, const float* __restrict__ w2,
    float* __restrict__ t0, float* __restrict__ t1, float* __restrict__ t2) {
    const int z = blockIdx.z;
    const float* W = z == 0 ? w0 : z == 1 ? w1 : w2;
    float* WT      = z == 0 ? t0 : z == 1 ? t1 : t2;
    __shared__ float tile[32][33];
    int tx = threadIdx.x & 31, ty = threadIdx.x >> 5;   // 32 x 8
    int x0 = blockIdx.x * 32, y0 = blockIdx.y * 32;
    #pragma unroll
    for (int i = 0; i < 32; i += 8)
        tile[ty + i][tx] = W[(size_t)(y0 + ty + i) * DIMD + x0 + tx];
    __syncthreads();
    #pragma unroll
    for (int i = 0; i < 32; i += 8)
        WT[(size_t)(x0 + ty + i) * DIMD + y0 + tx] = tile[tx][ty + i];
}

// ---------------------------------------------------------------------------
// Kernel 2: 3 projection GEMMs in one launch (z selects q/k/v).
//   P = X @ W via split-bf16 (3 MFMA per tile pair), outputs hi/lo bf16.
//   z==0 (Q) epilogue folds in scale*log2(e) so flash softmax uses exp2 directly.
// Block 256 thr (4 waves, 2x2), tile 128x128, BK=32. Grid (8,32,3)=768 blocks
// = 3 blocks/CU (LDS 40KB each -> fits).
// ---------------------------------------------------------------------------
__global__ __launch_bounds__(256, 3) void proj_split_gemm3(
    const float* __restrict__ xq, const float* __restrict__ xk, const float* __restrict__ xv,
    const float* __restrict__ wtq, const float* __restrict__ wtk, const float* __restrict__ wtv,
    unsigned short* __restrict__ qh, unsigned short* __restrict__ ql,
    unsigned short* __restrict__ kh, unsigned short* __restrict__ kl,
    unsigned short* __restrict__ vh, unsigned short* __restrict__ vl) {

    const int z = blockIdx.z;
    const float* X  = z == 0 ? xq  : z == 1 ? xk  : xv;
    const float* WT = z == 0 ? wtq : z == 1 ? wtk : wtv;
    unsigned short* outH = z == 0 ? qh : z == 1 ? kh : vh;
    unsigned short* outL = z == 0 ? ql : z == 1 ? kl : vl;
    const float oscale = z == 0 ? 0.0450842200278f : 1.0f;  // (1/32)*log2(e)

    // padded to 40 u16 (80B stride): 16B-aligned rows, 2-way bank alias (free)
    __shared__ unsigned short AsH[128][40], AsL[128][40], BsH[128][40], BsL[128][40];

    const int tid  = threadIdx.x;
    const int lane = tid & 63, wave = tid >> 6;
    const int quad = lane >> 4, l16 = lane & 15;
    const int wy = wave >> 1, wx = wave & 1;          // wave 64x64 subtile
    const int m0 = blockIdx.y * 128, n0 = blockIdx.x * 128;

    f32x4 acc[4][4];
    #pragma unroll
    for (int mt = 0; mt < 4; mt++)
        #pragma unroll
        for (int nt = 0; nt < 4; nt++) acc[mt][nt] = (f32x4)0.0f;

    for (int k0 = 0; k0 < DIMD; k0 += 32) {
        // stage A[128][32] and B[128][32] fp32 -> split hi/lo bf16 in LDS
        #pragma unroll
        for (int i = 0; i < 4; i++) {
            int f = i * 256 + tid;           // 1024 float4 chunks
            int r = f >> 3, c = (f & 7) * 4;
            f32x4 a  = *(const f32x4*)&X [(size_t)(m0 + r) * DIMD + k0 + c];
            f32x4 bb = *(const f32x4*)&WT[(size_t)(n0 + r) * DIMD + k0 + c];
            u16x4 ah, al, bh, bl;
            #pragma unroll
            for (int j = 0; j < 4; j++) {
                unsigned short hh, lll;
                split_bf16(a[j], hh, lll);  ah[j] = hh; al[j] = lll;
                split_bf16(bb[j], hh, lll); bh[j] = hh; bl[j] = lll;
            }
            *(u16x4*)&AsH[r][c] = ah;  *(u16x4*)&AsL[r][c] = al;
            *(u16x4*)&BsH[r][c] = bh;  *(u16x4*)&BsL[r][c] = bl;
        }
        __syncthreads();

        bf16x8 aH[4], aL[4], bH[4], bL[4];
        #pragma unroll
        for (int mt = 0; mt < 4; mt++) {
            int r = wy * 64 + mt * 16 + l16;
            aH[mt] = *(const bf16x8*)&AsH[r][quad * 8];
            aL[mt] = *(const bf16x8*)&AsL[r][quad * 8];
        }
        #pragma unroll
        for (int nt = 0; nt < 4; nt++) {
            int r = wx * 64 + nt * 16 + l16;
            bH[nt] = *(const bf16x8*)&BsH[r][quad * 8];
            bL[nt] = *(const bf16x8*)&BsL[r][quad * 8];
        }
        #pragma unroll
        for (int mt = 0; mt < 4; mt++)
            #pragma unroll
            for (int nt = 0; nt < 4; nt++) {
                acc[mt][nt] = mfma16(aH[mt], bH[nt], acc[mt][nt]);
                acc[mt][nt] = mfma16(aH[mt], bL[nt], acc[mt][nt]);
                acc[mt][nt] = mfma16(aL[mt], bH[nt], acc[mt][nt]);
            }
        __syncthreads();
    }

    // epilogue: scale (Q only) then split fp32 acc into hi/lo bf16 outputs
    #pragma unroll
    for (int mt = 0; mt < 4; mt++)
        #pragma unroll
        for (int nt = 0; nt < 4; nt++)
            #pragma unroll
            for (int r = 0; r < 4; r++) {
                int row = m0 + wy * 64 + mt * 16 + quad * 4 + r;
                int col = n0 + wx * 64 + nt * 16 + l16;
                unsigned short hh, lll;
                split_bf16(acc[mt][nt][r] * oscale, hh, lll);
                outH[(size_t)row * DIMD + col] = hh;
                outL[(size_t)row * DIMD + col] = lll;
            }
}

// ---------------------------------------------------------------------------
// Kernel 3: per-head V transpose: vh slab [bh][2048][64] -> vt [bh][64][2048]
// so flash can stage V^T with pure vector copies (no LDS scatter).
// Grid (32 seq-tiles, 32 bh), block 256.
// ---------------------------------------------------------------------------
__global__ __launch_bounds__(256) void transposeV(
    const unsigned short* __restrict__ vh, unsigned short* __restrict__ vt) {
    __shared__ unsigned short Ls[64][72];
    const int tid = threadIdx.x;
    const int bh = blockIdx.y;
    const int s0 = blockIdx.x * 64;
    const size_t slab = (size_t)bh * (SEQ * 64);
    #pragma unroll
    for (int i = 0; i < 2; i++) {
        int f = i * 256 + tid;
        int r = f >> 3, c = (f & 7) * 8;
        *(u16x8*)&Ls[r][c] = *(const u16x8*)(vh + slab + (size_t)(s0 + r) * 64 + c);
    }
    __syncthreads();
    #pragma unroll
    for (int i = 0; i < 2; i++) {
        int f = i * 256 + tid;
        int d = f >> 3, j = (f & 7) * 8;
        u16x8 o;
        #pragma unroll
        for (int jj = 0; jj < 8; jj++) o[jj] = Ls[j + jj][d];
        *(u16x8*)(vt + slab + (size_t)d * SEQ + s0 + j) = o;
    }
}

// ---------------------------------------------------------------------------
// Kernel 4: flash attention per (b,h): S=2048, hd=64. Q pre-scaled by
// scale*log2(e) so softmax is exp2(S - M). QK^T split-bf16 (3 MFMA), PV bf16.
// Q-tile 64 rows/block (4 waves x 16 rows), KV-tile 64/iter.
// Grid (32,32)=1024 blocks = 4 blocks/CU; LDS 36.9KB.
// ---------------------------------------------------------------------------
__global__ __launch_bounds__(256, 4) void flash_attn(
    const unsigned short* __restrict__ qh, const unsigned short* __restrict__ ql,
    const unsigned short* __restrict__ kh, const unsigned short* __restrict__ kl,
    const unsigned short* __restrict__ vt,
    float* __restrict__ out) {

    // all strides 72 u16 = 144B: 16B-aligned, 2-way bank alias (free)
    __shared__ unsigned short KsH[64][72], KsL[64][72], VTs[64][72];
    __shared__ unsigned short Ps[4][16][72];

    const int tid  = threadIdx.x;
    const int lane = tid & 63, wave = tid >> 6;
    const int quad = lane >> 4, l16 = lane & 15;
    const int bh = blockIdx.y, b = bh >> 4, h = bh & 15;
    const size_t slab = (size_t)bh * (SEQ * 64);   // head slab (elems)
    const int q0 = blockIdx.x * 64;

    // Q fragments in registers (hi/lo); wave owns rows q0+wave*16 .. +15
    bf16x8 qfH[2], qfL[2];
    {
        int r2 = q0 + wave * 16 + l16;
        #pragma unroll
        for (int kk = 0; kk < 2; kk++) {
            int c = kk * 32 + quad * 8;
            qfH[kk] = *(const bf16x8*)(qh + slab + (size_t)r2 * 64 + c);
            qfL[kk] = *(const bf16x8*)(ql + slab + (size_t)r2 * 64 + c);
        }
    }

    f32x4 O[4];
    float M[4], L[4];
    #pragma unroll
    for (int r = 0; r < 4; r++) { M[r] = -3.0e38f; L[r] = 0.0f; }
    #pragma unroll
    for (int nv = 0; nv < 4; nv++) O[nv] = (f32x4)0.0f;

    for (int j0 = 0; j0 < SEQ; j0 += 64) {
        // stage K hi/lo [64][64] and V^T [64 hd][64 keys] (all vector copies)
        #pragma unroll
        for (int i = 0; i < 2; i++) {
            int f = i * 256 + tid;
            int r = f >> 3, c = (f & 7) * 8;
            const size_t g = slab + (size_t)(j0 + r) * 64 + c;
            *(u16x8*)&KsH[r][c] = *(const u16x8*)(kh + g);
            *(u16x8*)&KsL[r][c] = *(const u16x8*)(kl + g);
            *(u16x8*)&VTs[r][c] = *(const u16x8*)(vt + slab + (size_t)r * SEQ + j0 + c);
        }
        __syncthreads();

        // S = Q K^T (split: Ah*Bh + Ah*Bl + Al*Bh), already in log2 domain
        f32x4 S[4];
        #pragma unroll
        for (int nt = 0; nt < 4; nt++) S[nt] = (f32x4)0.0f;
        #pragma unroll
        for (int nt = 0; nt < 4; nt++)
            #pragma unroll
            for (int kk = 0; kk < 2; kk++) {
                int rB = nt * 16 + l16, cB = kk * 32 + quad * 8;
                bf16x8 bH = *(const bf16x8*)&KsH[rB][cB];
                bf16x8 bL = *(const bf16x8*)&KsL[rB][cB];
                S[nt] = mfma16(qfH[kk], bH, S[nt]);
                S[nt] = mfma16(qfH[kk], bL, S[nt]);
                S[nt] = mfma16(qfL[kk], bH, S[nt]);
            }

        // online softmax: row (quad*4+r) stats are register-local per lane
        #pragma unroll
        for (int r = 0; r < 4; r++) {
            float mx = fmaxf(fmaxf(S[0][r], S[1][r]), fmaxf(S[2][r], S[3][r]));
            #pragma unroll
            for (int d = 1; d < 16; d <<= 1) mx = fmaxf(mx, __shfl_xor(mx, d));
            float Mn = fmaxf(M[r], mx);
            float al = fast_exp2(M[r] - Mn);
            M[r] = Mn;
            float rs = 0.0f;
            #pragma unroll
            for (int nt = 0; nt < 4; nt++) {
                float p = fast_exp2(S[nt][r] - Mn);
                S[nt][r] = p;
                rs += p;
            }
            #pragma unroll
            for (int d = 1; d < 16; d <<= 1) rs += __shfl_xor(rs, d);
            L[r] = L[r] * al + rs;
            #pragma unroll
            for (int nv = 0; nv < 4; nv++) O[nv][r] *= al;
            int prow = quad * 4 + r;
            #pragma unroll
            for (int nt = 0; nt < 4; nt++)
                Ps[wave][prow][nt * 16 + l16] =
                    (unsigned short)(__float_as_uint(S[nt][r]) >> 16);
        }

        // O += P @ V  (bf16)
        #pragma unroll
        for (int kk = 0; kk < 2; kk++) {
            bf16x8 aP = *(const bf16x8*)&Ps[wave][l16][kk * 32 + quad * 8];
            #pragma unroll
            for (int nv = 0; nv < 4; nv++) {
                bf16x8 bV = *(const bf16x8*)&VTs[nv * 16 + l16][kk * 32 + quad * 8];
                O[nv] = mfma16(aP, bV, O[nv]);
            }
        }
        __syncthreads();
    }

    // epilogue: out[b, row, h*64 + d] = O / L
    #pragma unroll
    for (int r = 0; r < 4; r++) {
        float inv = 1.0f / L[r];
        int row = q0 + wave * 16 + quad * 4 + r;
        size_t obase = ((size_t)(b * SEQ + row)) * DIMD + h * 64;
        #pragma unroll
        for (int nv = 0; nv < 4; nv++)
            out[obase + nv * 16 + l16] = O[nv][r] * inv;
    }
}

// ---------------------------------------------------------------------------
extern "C" void kernel_launch(void* const* d_in, const int* in_sizes, int n_in,
                              void* d_out, int out_size, void* d_ws, size_t ws_size,
                              hipStream_t stream) {
    const float* q  = (const float*)d_in[0];
    const float* k  = (const float*)d_in[1];
    const float* v  = (const float*)d_in[2];
    const float* wq = (const float*)d_in[3];
    const float* wk = (const float*)d_in[4];
    const float* wv = (const float*)d_in[5];
    float* out = (float*)d_out;

    char* ws = (char*)d_ws;
    const size_t WT_BYTES = (size_t)DIMD * DIMD * 4;       // 4 MB
    const size_t BF_BYTES = (size_t)MROWS * DIMD * 2;      // 8 MB
    float* WTq = (float*)(ws + 0 * WT_BYTES);
    float* WTk = (float*)(ws + 1 * WT_BYTES);
    float* WTv = (float*)(ws + 2 * WT_BYTES);
    unsigned short* qh = (unsigned short*)(ws + 3 * WT_BYTES + 0 * BF_BYTES);
    unsigned short* ql = (unsigned short*)(ws + 3 * WT_BYTES + 1 * BF_BYTES);
    unsigned short* kh = (unsigned short*)(ws + 3 * WT_BYTES + 2 * BF_BYTES);
    unsigned short* kl = (unsigned short*)(ws + 3 * WT_BYTES + 3 * BF_BYTES);
    unsigned short* vh = (unsigned short*)(ws + 3 * WT_BYTES + 4 * BF_BYTES);
    unsigned short* vl = (unsigned short*)(ws + 3 * WT_BYTES + 5 * BF_BYTES);
    unsigned short* vt = (unsigned short*)(ws + 3 * WT_BYTES + 6 * BF_BYTES);

    transposeW3<<<dim3(32, 32, 3), 256, 0, stream>>>(wq, wk, wv, WTq, WTk, WTv);

    proj_split_gemm3<<<dim3(DIMD / 128, MROWS / 128, 3), 256, 0, stream>>>(
        q, k, v, WTq, WTk, WTv, qh, ql, kh, kl, vh, vl);

    transposeV<<<dim3(SEQ / 64, 2 * NH), 256, 0, stream>>>(vh, vt);

    flash_attn<<<dim3(SEQ / 64, 2 * NH), 256, 0, stream>>>(qh, ql, kh, kl, vt, out);
}